// Round 1
// baseline (294.776 us; speedup 1.0000x reference)
//
#include <hip/hip_runtime.h>
#include <hip/hip_bf16.h>

#define BDIM 256

constexpr int Vv = 3, Cc = 64, Hh = 96, Ww = 96, Dd = 48;
constexpr int HW = Hh * Ww;          // 9216
constexpr int NPIX = Dd * HW;        // 442368
constexpr int DHW = Dd * HW;         // channel stride in output

__device__ __forceinline__ float ldf(const float* p) { return *p; }
__device__ __forceinline__ float ldf(const __hip_bfloat16* p) { return __bfloat162float(*p); }
__device__ __forceinline__ void stf(float* p, float v) { *p = v; }
__device__ __forceinline__ void stf(__hip_bfloat16* p, float v) { *p = __float2bfloat16(v); }

template <typename T>
__device__ __forceinline__ void body(const T* __restrict__ imgs, const T* __restrict__ feats,
                                     const T* __restrict__ proj, const T* __restrict__ depthv,
                                     T* __restrict__ out, int idx)
{
    const int w = idx % Ww;
    const int t = idx / Ww;
    const int h = t % Hh;
    const int d = t / Hh;
    const int ohw = h * Ww + w;

    const float xf = (float)w, yf = (float)h;
    const float depth = ldf(depthv + d);

    int offs[2][4];
    float wts[2][4];
    float msum = 1.0f;

#pragma unroll
    for (int v = 0; v < 2; ++v) {
#pragma clang fp contract(off)
        // view v+1 projection: rows of 3x4 [R | T]
        const T* P = proj + (v + 1) * 12;
        const float r00 = ldf(P + 0), r01 = ldf(P + 1), r02 = ldf(P + 2), t0 = ldf(P + 3);
        const float r10 = ldf(P + 4), r11 = ldf(P + 5), r12 = ldf(P + 6), t1 = ldf(P + 7);
        const float r20 = ldf(P + 8), r21 = ldf(P + 9), r22 = ldf(P + 10), t2 = ldf(P + 11);

        // pts = R @ [x,y,1] + T/depth  (match numpy op order: (r0*x + r1*y) + r2, then + T/depth)
        const float px = ((r00 * xf + r01 * yf) + r02) + t0 / depth;
        const float py = ((r10 * xf + r11 * yf) + r12) + t1 / depth;
        const float pz = ((r20 * xf + r21 * yf) + r22) + t2 / depth;

        const float xy0 = px / pz;
        const float xy1 = py / pz;
        const float gx = xy0 / ((float)(Ww - 1) * 0.5f) - 1.0f;
        const float gy = xy1 / ((float)(Hh - 1) * 0.5f) - 1.0f;

        // strict in-bounds mask (NaN-safe: comparisons false => 0)
        const bool inb = (gx > -1.0f) && (gx < 1.0f) && (gy > -1.0f) && (gy < 1.0f);
        msum += inb ? 1.0f : 0.0f;

        // back to pixel coords, same op order as reference
        const float sx = (gx + 1.0f) * 0.5f * (float)(Ww - 1);
        const float sy = (gy + 1.0f) * 0.5f * (float)(Hh - 1);
        const float x0 = floorf(sx), y0 = floorf(sy);
        const float wx1 = sx - x0, wy1 = sy - y0;
        const float wx0 = 1.0f - wx1, wy0 = 1.0f - wy1;

#pragma unroll
        for (int k = 0; k < 4; ++k) {
            const float xi = (k & 1) ? (x0 + 1.0f) : x0;
            const float yi = (k & 2) ? (y0 + 1.0f) : y0;
            const float wk = ((k & 1) ? wx1 : wx0) * ((k & 2) ? wy1 : wy0);
            const bool valid = (xi >= 0.0f) && (xi <= (float)(Ww - 1)) &&
                               (yi >= 0.0f) && (yi <= (float)(Hh - 1));
            // clamp in float first (NaN/huge-safe), then convert
            const float xc = fminf(fmaxf(xi, 0.0f), (float)(Ww - 1));
            const float yc = fminf(fmaxf(yi, 0.0f), (float)(Hh - 1));
            offs[v][k] = (int)yc * Ww + (int)xc;
            wts[v][k] = valid ? wk : 0.0f;
        }
    }

    const int obase = d * HW + ohw;

    // channels 0..2: ref image broadcast over depth
#pragma unroll
    for (int c = 0; c < 3; ++c) {
        stf(out + c * DHW + obase, ldf(imgs + c * HW + ohw));
    }

    // channels 3..8: warped images, views 1 and 2
#pragma unroll
    for (int v = 0; v < 2; ++v) {
        const T* ib = imgs + (v + 1) * 3 * HW;
#pragma unroll
        for (int c = 0; c < 3; ++c) {
            const T* p = ib + c * HW;
            const float acc = wts[v][0] * ldf(p + offs[v][0]) + wts[v][1] * ldf(p + offs[v][1]) +
                              wts[v][2] * ldf(p + offs[v][2]) + wts[v][3] * ldf(p + offs[v][3]);
            stf(out + (3 * (v + 1) + c) * DHW + obase, acc);
        }
    }

    // channels 9..72: variance over {ref, wv1, wv2}
    const float count = 1.0f / msum;
    const T* f0 = feats;
    const T* f1 = feats + Cc * HW;
    const T* f2 = feats + 2 * Cc * HW;
#pragma unroll 8
    for (int c = 0; c < Cc; ++c) {
        const float fr = ldf(f0 + c * HW + ohw);
        const T* p1 = f1 + c * HW;
        const T* p2 = f2 + c * HW;
        const float a1 = wts[0][0] * ldf(p1 + offs[0][0]) + wts[0][1] * ldf(p1 + offs[0][1]) +
                         wts[0][2] * ldf(p1 + offs[0][2]) + wts[0][3] * ldf(p1 + offs[0][3]);
        const float a2 = wts[1][0] * ldf(p2 + offs[1][0]) + wts[1][1] * ldf(p2 + offs[1][1]) +
                         wts[1][2] * ldf(p2 + offs[1][2]) + wts[1][3] * ldf(p2 + offs[1][3]);
        const float s = fr + a1 + a2;
        const float sq = fr * fr + a1 * a1 + a2 * a2;
        const float sc = s * count;
        stf(out + (3 * Vv + c) * DHW + obase, sq * count - sc * sc);
    }
}

// Detect input dtype on-device: read imgs as bf16 halfwords. If the buffer is
// really f32, the low-16-bit mantissa words decode to huge bf16 magnitudes.
__global__ void detect_dtype_kernel(const unsigned short* __restrict__ raw, int n, int* flag)
{
    __shared__ float red[BDIM];
    float m = 0.0f;
    for (int i = threadIdx.x; i < n; i += BDIM) {
        unsigned int bits = ((unsigned int)raw[i]) << 16;
        m = fmaxf(m, fabsf(__uint_as_float(bits)));  // NaN halfwords ignored by fmaxf
    }
    red[threadIdx.x] = m;
    __syncthreads();
    for (int s = BDIM / 2; s > 0; s >>= 1) {
        if (threadIdx.x < s) red[threadIdx.x] = fmaxf(red[threadIdx.x], red[threadIdx.x + s]);
        __syncthreads();
    }
    if (threadIdx.x == 0) flag[0] = (red[0] > 1e4f) ? 1 : 0;  // 1 => data is f32
}

__global__ void __launch_bounds__(BDIM) grid_encoder_kernel(
    const void* __restrict__ imgs, const void* __restrict__ feats,
    const void* __restrict__ proj, const void* __restrict__ depthv,
    void* __restrict__ out, const int* __restrict__ flag)
{
    const int idx = blockIdx.x * BDIM + threadIdx.x;
    if (idx >= NPIX) return;
    if (*flag) {
        body<float>((const float*)imgs, (const float*)feats, (const float*)proj,
                    (const float*)depthv, (float*)out, idx);
    } else {
        body<__hip_bfloat16>((const __hip_bfloat16*)imgs, (const __hip_bfloat16*)feats,
                             (const __hip_bfloat16*)proj, (const __hip_bfloat16*)depthv,
                             (__hip_bfloat16*)out, idx);
    }
}

extern "C" void kernel_launch(void* const* d_in, const int* in_sizes, int n_in,
                              void* d_out, int out_size, void* d_ws, size_t ws_size,
                              hipStream_t stream)
{
    const void* imgs   = d_in[0];
    const void* feats  = d_in[1];
    const void* proj   = d_in[2];
    const void* depthv = d_in[3];
    int* flag = (int*)d_ws;

    detect_dtype_kernel<<<1, BDIM, 0, stream>>>((const unsigned short*)imgs, 4096, flag);

    const int blocks = (NPIX + BDIM - 1) / BDIM;  // 1728
    grid_encoder_kernel<<<blocks, BDIM, 0, stream>>>(imgs, feats, proj, depthv, d_out, flag);
}

// Round 2
// 209.824 us; speedup vs baseline: 1.4049x; 1.4049x over previous
//
#include <hip/hip_runtime.h>

#define BDIM 256

constexpr int Vv = 3, Cc = 64, Hh = 96, Ww = 96, Dd = 48;
constexpr int HW = Hh * Ww;          // 9216
constexpr int NPIX = Dd * HW;        // 442368
constexpr int DHW = Dd * HW;         // output channel stride

// ---------------------------------------------------------------------------
// Shared coordinate/weight computation (identical numerics to round-1 pass).
// ---------------------------------------------------------------------------
__device__ __forceinline__ void compute_warp(const float* __restrict__ proj, float depth,
                                             float xf, float yf,
                                             int offs[2][4], float wts[2][4], float& msum)
{
    msum = 1.0f;
#pragma unroll
    for (int v = 0; v < 2; ++v) {
#pragma clang fp contract(off)
        const float* P = proj + (v + 1) * 12;
        const float r00 = P[0], r01 = P[1], r02 = P[2],  t0 = P[3];
        const float r10 = P[4], r11 = P[5], r12 = P[6],  t1 = P[7];
        const float r20 = P[8], r21 = P[9], r22 = P[10], t2 = P[11];

        const float px = ((r00 * xf + r01 * yf) + r02) + t0 / depth;
        const float py = ((r10 * xf + r11 * yf) + r12) + t1 / depth;
        const float pz = ((r20 * xf + r21 * yf) + r22) + t2 / depth;

        const float xy0 = px / pz;
        const float xy1 = py / pz;
        const float gx = xy0 / ((float)(Ww - 1) * 0.5f) - 1.0f;
        const float gy = xy1 / ((float)(Hh - 1) * 0.5f) - 1.0f;

        const bool inb = (gx > -1.0f) && (gx < 1.0f) && (gy > -1.0f) && (gy < 1.0f);
        msum += inb ? 1.0f : 0.0f;

        const float sx = (gx + 1.0f) * 0.5f * (float)(Ww - 1);
        const float sy = (gy + 1.0f) * 0.5f * (float)(Hh - 1);
        const float x0 = floorf(sx), y0 = floorf(sy);
        const float wx1 = sx - x0, wy1 = sy - y0;
        const float wx0 = 1.0f - wx1, wy0 = 1.0f - wy1;

#pragma unroll
        for (int k = 0; k < 4; ++k) {
            const float xi = (k & 1) ? (x0 + 1.0f) : x0;
            const float yi = (k & 2) ? (y0 + 1.0f) : y0;
            const float wk = ((k & 1) ? wx1 : wx0) * ((k & 2) ? wy1 : wy0);
            const bool valid = (xi >= 0.0f) && (xi <= (float)(Ww - 1)) &&
                               (yi >= 0.0f) && (yi <= (float)(Hh - 1));
            const float xc = fminf(fmaxf(xi, 0.0f), (float)(Ww - 1));
            const float yc = fminf(fmaxf(yi, 0.0f), (float)(Hh - 1));
            offs[v][k] = (int)yc * Ww + (int)xc;
            wts[v][k] = valid ? wk : 0.0f;
        }
    }
}

// ---------------------------------------------------------------------------
// feats (V, C, HW) -> ft (V, HW, C)   (channel-minor for vectorized gathers)
// ---------------------------------------------------------------------------
__global__ void __launch_bounds__(BDIM) transpose_feats_kernel(const float* __restrict__ feats,
                                                               float* __restrict__ ft)
{
    __shared__ float tile[64][65];
    const int v  = blockIdx.y;
    const int p0 = blockIdx.x * 64;
    const float* src = feats + (size_t)v * Cc * HW;

    const int px = threadIdx.x & 63;
    const int c0 = threadIdx.x >> 6;
#pragma unroll
    for (int c = c0; c < Cc; c += 4)
        tile[c][px] = src[(size_t)c * HW + p0 + px];
    __syncthreads();

    const int cc  = threadIdx.x & 63;
    const int pr0 = threadIdx.x >> 6;
    float* dst = ft + ((size_t)v * HW + p0) * Cc;
#pragma unroll
    for (int p = pr0; p < 64; p += 4)
        dst[p * Cc + cc] = tile[cc][p];
}

// ---------------------------------------------------------------------------
// imgs views 1..2 (3, HW) -> it (2, HW, 4)  (padded channel-minor)
// ---------------------------------------------------------------------------
__global__ void __launch_bounds__(BDIM) transpose_imgs_kernel(const float* __restrict__ imgs,
                                                              float* __restrict__ it)
{
    const int idx = blockIdx.x * BDIM + threadIdx.x;
    if (idx >= 2 * HW) return;
    const int v = idx / HW;
    const int p = idx - v * HW;
    const float* src = imgs + (size_t)(v + 1) * 3 * HW + p;
    float4 o;
    o.x = src[0];
    o.y = src[HW];
    o.z = src[2 * HW];
    o.w = 0.0f;
    ((float4*)it)[idx] = o;
}

// ---------------------------------------------------------------------------
// main fused kernel: thread per (d,h,w) output pixel
// ---------------------------------------------------------------------------
__global__ void __launch_bounds__(BDIM, 4) ge_main_kernel(
    const float* __restrict__ imgs, const float* __restrict__ ftr,
    const float* __restrict__ it, const float* __restrict__ proj,
    const float* __restrict__ depthv, float* __restrict__ out)
{
    const int idx = blockIdx.x * BDIM + threadIdx.x;
    if (idx >= NPIX) return;
    const int w = idx % Ww;
    const int t = idx / Ww;
    const int h = t % Hh;
    const int d = t / Hh;
    const int ohw = h * Ww + w;

    int offs[2][4];
    float wts[2][4];
    float msum;
    compute_warp(proj, depthv[d], (float)w, (float)h, offs, wts, msum);

    const int obase = d * HW + ohw;

    // channels 0..2: ref image broadcast over depth (coalesced load + store)
#pragma unroll
    for (int c = 0; c < 3; ++c)
        out[c * DHW + obase] = imgs[c * HW + ohw];

    // channels 3..8: warped images — one float4 per corner from padded layout
    const float4* itv = (const float4*)it;
#pragma unroll
    for (int v = 0; v < 2; ++v) {
        const float4 p0 = itv[(size_t)v * HW + offs[v][0]];
        const float4 p1 = itv[(size_t)v * HW + offs[v][1]];
        const float4 p2 = itv[(size_t)v * HW + offs[v][2]];
        const float4 p3 = itv[(size_t)v * HW + offs[v][3]];
        const float w0 = wts[v][0], w1 = wts[v][1], w2 = wts[v][2], w3 = wts[v][3];
        out[(3 * (v + 1) + 0) * DHW + obase] = w0 * p0.x + w1 * p1.x + w2 * p2.x + w3 * p3.x;
        out[(3 * (v + 1) + 1) * DHW + obase] = w0 * p0.y + w1 * p1.y + w2 * p2.y + w3 * p3.y;
        out[(3 * (v + 1) + 2) * DHW + obase] = w0 * p0.z + w1 * p1.z + w2 * p2.z + w3 * p3.z;
    }

    // channels 9..72: variance over {ref, wv1, wv2}; channel-minor gathers
    const float count = 1.0f / msum;
    const float4* f0  = (const float4*)ftr + (size_t)ohw * 16;
    const float4* c10 = (const float4*)ftr + ((size_t)HW + offs[0][0]) * 16;
    const float4* c11 = (const float4*)ftr + ((size_t)HW + offs[0][1]) * 16;
    const float4* c12 = (const float4*)ftr + ((size_t)HW + offs[0][2]) * 16;
    const float4* c13 = (const float4*)ftr + ((size_t)HW + offs[0][3]) * 16;
    const float4* c20 = (const float4*)ftr + ((size_t)2 * HW + offs[1][0]) * 16;
    const float4* c21 = (const float4*)ftr + ((size_t)2 * HW + offs[1][1]) * 16;
    const float4* c22 = (const float4*)ftr + ((size_t)2 * HW + offs[1][2]) * 16;
    const float4* c23 = (const float4*)ftr + ((size_t)2 * HW + offs[1][3]) * 16;
    const float w00 = wts[0][0], w01 = wts[0][1], w02 = wts[0][2], w03 = wts[0][3];
    const float w10 = wts[1][0], w11 = wts[1][1], w12 = wts[1][2], w13 = wts[1][3];
    float* ob = out + 9 * DHW + obase;

#define VARCOMP(comp, cidx)                                                     \
    do {                                                                        \
        const float A_ = w00 * a0.comp + w01 * a1.comp + w02 * a2.comp + w03 * a3.comp; \
        const float B_ = w10 * b0.comp + w11 * b1.comp + w12 * b2.comp + w13 * b3.comp; \
        const float S_ = fr.comp + A_ + B_;                                     \
        const float Q_ = fr.comp * fr.comp + A_ * A_ + B_ * B_;                 \
        const float sc_ = S_ * count;                                           \
        ob[(size_t)(4 * j + (cidx)) * DHW] = Q_ * count - sc_ * sc_;            \
    } while (0)

#pragma unroll 4
    for (int j = 0; j < 16; ++j) {
        const float4 fr = f0[j];
        const float4 a0 = c10[j], a1 = c11[j], a2 = c12[j], a3 = c13[j];
        const float4 b0 = c20[j], b1 = c21[j], b2 = c22[j], b3 = c23[j];
        VARCOMP(x, 0);
        VARCOMP(y, 1);
        VARCOMP(z, 2);
        VARCOMP(w, 3);
    }
#undef VARCOMP
}

// ---------------------------------------------------------------------------
// fallback (round-1 style, no workspace) — only used if ws_size is too small
// ---------------------------------------------------------------------------
__global__ void __launch_bounds__(BDIM) ge_direct_kernel(
    const float* __restrict__ imgs, const float* __restrict__ feats,
    const float* __restrict__ proj, const float* __restrict__ depthv,
    float* __restrict__ out)
{
    const int idx = blockIdx.x * BDIM + threadIdx.x;
    if (idx >= NPIX) return;
    const int w = idx % Ww;
    const int t = idx / Ww;
    const int h = t % Hh;
    const int d = t / Hh;
    const int ohw = h * Ww + w;

    int offs[2][4];
    float wts[2][4];
    float msum;
    compute_warp(proj, depthv[d], (float)w, (float)h, offs, wts, msum);

    const int obase = d * HW + ohw;
#pragma unroll
    for (int c = 0; c < 3; ++c)
        out[c * DHW + obase] = imgs[c * HW + ohw];

#pragma unroll
    for (int v = 0; v < 2; ++v) {
        const float* ib = imgs + (size_t)(v + 1) * 3 * HW;
#pragma unroll
        for (int c = 0; c < 3; ++c) {
            const float* p = ib + (size_t)c * HW;
            const float acc = wts[v][0] * p[offs[v][0]] + wts[v][1] * p[offs[v][1]] +
                              wts[v][2] * p[offs[v][2]] + wts[v][3] * p[offs[v][3]];
            out[(3 * (v + 1) + c) * DHW + obase] = acc;
        }
    }

    const float count = 1.0f / msum;
    const float* f0 = feats;
    const float* f1 = feats + (size_t)Cc * HW;
    const float* f2 = feats + (size_t)2 * Cc * HW;
#pragma unroll 8
    for (int c = 0; c < Cc; ++c) {
        const float fr = f0[(size_t)c * HW + ohw];
        const float* p1 = f1 + (size_t)c * HW;
        const float* p2 = f2 + (size_t)c * HW;
        const float a1 = wts[0][0] * p1[offs[0][0]] + wts[0][1] * p1[offs[0][1]] +
                         wts[0][2] * p1[offs[0][2]] + wts[0][3] * p1[offs[0][3]];
        const float a2 = wts[1][0] * p2[offs[1][0]] + wts[1][1] * p2[offs[1][1]] +
                         wts[1][2] * p2[offs[1][2]] + wts[1][3] * p2[offs[1][3]];
        const float s = fr + a1 + a2;
        const float sq = fr * fr + a1 * a1 + a2 * a2;
        const float sc = s * count;
        out[(3 * Vv + c) * DHW + obase] = sq * count - sc * sc;
    }
}

extern "C" void kernel_launch(void* const* d_in, const int* in_sizes, int n_in,
                              void* d_out, int out_size, void* d_ws, size_t ws_size,
                              hipStream_t stream)
{
    const float* imgs   = (const float*)d_in[0];
    const float* feats  = (const float*)d_in[1];
    const float* proj   = (const float*)d_in[2];
    const float* depthv = (const float*)d_in[3];
    float* out = (float*)d_out;

    const size_t need = (size_t)Vv * HW * Cc * sizeof(float)      // ftr: 7.08 MB
                      + (size_t)2 * HW * 4 * sizeof(float);       // it:  0.29 MB
    const int blocks = (NPIX + BDIM - 1) / BDIM;  // 1728

    if (ws_size >= need) {
        float* ftr = (float*)d_ws;
        float* it  = ftr + (size_t)Vv * HW * Cc;
        dim3 g1(HW / 64, Vv);
        transpose_feats_kernel<<<g1, BDIM, 0, stream>>>(feats, ftr);
        transpose_imgs_kernel<<<(2 * HW + BDIM - 1) / BDIM, BDIM, 0, stream>>>(imgs, it);
        ge_main_kernel<<<blocks, BDIM, 0, stream>>>(imgs, ftr, it, proj, depthv, out);
    } else {
        ge_direct_kernel<<<blocks, BDIM, 0, stream>>>(imgs, feats, proj, depthv, out);
    }
}

// Round 3
// 180.640 us; speedup vs baseline: 1.6318x; 1.1616x over previous
//
#include <hip/hip_runtime.h>

#define BDIM 256

constexpr int Vv = 3, Cc = 64, Hh = 96, Ww = 96, Dd = 48;
constexpr int HW = Hh * Ww;          // 9216
constexpr int NPIX = Dd * HW;        // 442368
constexpr int DHW = Dd * HW;         // output channel stride

// ---------------------------------------------------------------------------
// Shared coordinate/weight computation (identical numerics to round-1/2 pass).
// ---------------------------------------------------------------------------
__device__ __forceinline__ void compute_warp(const float* __restrict__ proj, float depth,
                                             float xf, float yf,
                                             int offs[2][4], float wts[2][4], float& msum)
{
    msum = 1.0f;
#pragma unroll
    for (int v = 0; v < 2; ++v) {
#pragma clang fp contract(off)
        const float* P = proj + (v + 1) * 12;
        const float r00 = P[0], r01 = P[1], r02 = P[2],  t0 = P[3];
        const float r10 = P[4], r11 = P[5], r12 = P[6],  t1 = P[7];
        const float r20 = P[8], r21 = P[9], r22 = P[10], t2 = P[11];

        const float px = ((r00 * xf + r01 * yf) + r02) + t0 / depth;
        const float py = ((r10 * xf + r11 * yf) + r12) + t1 / depth;
        const float pz = ((r20 * xf + r21 * yf) + r22) + t2 / depth;

        const float xy0 = px / pz;
        const float xy1 = py / pz;
        const float gx = xy0 / ((float)(Ww - 1) * 0.5f) - 1.0f;
        const float gy = xy1 / ((float)(Hh - 1) * 0.5f) - 1.0f;

        const bool inb = (gx > -1.0f) && (gx < 1.0f) && (gy > -1.0f) && (gy < 1.0f);
        msum += inb ? 1.0f : 0.0f;

        const float sx = (gx + 1.0f) * 0.5f * (float)(Ww - 1);
        const float sy = (gy + 1.0f) * 0.5f * (float)(Hh - 1);
        const float x0 = floorf(sx), y0 = floorf(sy);
        const float wx1 = sx - x0, wy1 = sy - y0;
        const float wx0 = 1.0f - wx1, wy0 = 1.0f - wy1;

#pragma unroll
        for (int k = 0; k < 4; ++k) {
            const float xi = (k & 1) ? (x0 + 1.0f) : x0;
            const float yi = (k & 2) ? (y0 + 1.0f) : y0;
            const float wk = ((k & 1) ? wx1 : wx0) * ((k & 2) ? wy1 : wy0);
            const bool valid = (xi >= 0.0f) && (xi <= (float)(Ww - 1)) &&
                               (yi >= 0.0f) && (yi <= (float)(Hh - 1));
            const float xc = fminf(fmaxf(xi, 0.0f), (float)(Ww - 1));
            const float yc = fminf(fmaxf(yi, 0.0f), (float)(Hh - 1));
            offs[v][k] = (int)yc * Ww + (int)xc;
            wts[v][k] = valid ? wk : 0.0f;
        }
    }
}

// ---------------------------------------------------------------------------
// feats (V, C, HW) -> ftr (V, HW, C)   (channel-minor for coalesced lane=C reads)
// ---------------------------------------------------------------------------
__global__ void __launch_bounds__(BDIM) transpose_feats_kernel(const float* __restrict__ feats,
                                                               float* __restrict__ ft)
{
    __shared__ float tile[64][65];
    const int v  = blockIdx.y;
    const int p0 = blockIdx.x * 64;
    const float* src = feats + (size_t)v * Cc * HW;

    const int px = threadIdx.x & 63;
    const int c0 = threadIdx.x >> 6;
#pragma unroll
    for (int c = c0; c < Cc; c += 4)
        tile[c][px] = src[(size_t)c * HW + p0 + px];
    __syncthreads();

    const int cc  = threadIdx.x & 63;
    const int pr0 = threadIdx.x >> 6;
    float* dst = ft + ((size_t)v * HW + p0) * Cc;
#pragma unroll
    for (int p = pr0; p < 64; p += 4)
        dst[p * Cc + cc] = tile[cc][p];
}

// ---------------------------------------------------------------------------
// main kernel: one block per (d, h) row of 96 pixels.
// Phase 1: per-pixel warp coords -> LDS; ref-img copy + warped-img channels.
// Phase 2: wave = pixel (24 pixels/wave), lane = channel; coalesced 256B loads.
// Phase 3: coalesced store of the 64x96 variance tile.
// ---------------------------------------------------------------------------
__global__ void __launch_bounds__(BDIM) ge_row_kernel(
    const float* __restrict__ imgs, const float* __restrict__ ftr,
    const float* __restrict__ proj, const float* __restrict__ depthv,
    float* __restrict__ out)
{
    __shared__ float s_tile[Cc][Ww + 1];     // 64 x 97 floats, bank-safe
    __shared__ int   s_base[2][4][Ww];       // ftr element index of each corner
    __shared__ float s_wt[2][4][Ww];
    __shared__ float s_cnt[Ww];

    const int blk = blockIdx.x;              // d*Hh + h
    const int d   = blk / Hh;
    const int h   = blk % Hh;
    const int tid = threadIdx.x;
    const int rowbase = d * HW + h * Ww;     // output offset of (d,h,0)

    // ---- Phase 1 ----
    if (tid < Ww) {
        const int w = tid;
        int offs[2][4];
        float wts[2][4];
        float msum;
        compute_warp(proj, depthv[d], (float)w, (float)h, offs, wts, msum);
        s_cnt[w] = 1.0f / msum;
#pragma unroll
        for (int v = 0; v < 2; ++v)
#pragma unroll
            for (int k = 0; k < 4; ++k) {
                s_base[v][k][w] = ((v + 1) * HW + offs[v][k]) * Cc;
                s_wt[v][k][w]   = wts[v][k];
            }

        const int hw = h * Ww + w;
        // channels 0..2: ref image broadcast over depth
#pragma unroll
        for (int c = 0; c < 3; ++c)
            out[c * DHW + rowbase + w] = imgs[c * HW + hw];

        // channels 3..8: warped images (gathers near-coalesced in channel-major layout)
#pragma unroll
        for (int v = 0; v < 2; ++v) {
            const float* ib = imgs + (size_t)(v + 1) * 3 * HW;
#pragma unroll
            for (int c = 0; c < 3; ++c) {
                const float* p = ib + (size_t)c * HW;
                const float acc = wts[v][0] * p[offs[v][0]] + wts[v][1] * p[offs[v][1]] +
                                  wts[v][2] * p[offs[v][2]] + wts[v][3] * p[offs[v][3]];
                out[(3 * (v + 1) + c) * DHW + rowbase + w] = acc;
            }
        }
    }
    __syncthreads();

    // ---- Phase 2 ----
    {
        const int wave = tid >> 6;
        const int c    = tid & 63;
        const int p0   = wave * (Ww / 4);    // 24 pixels per wave
#pragma unroll 2
        for (int i = 0; i < Ww / 4; ++i) {
            const int p = p0 + i;
            const float cnt = s_cnt[p];
            const int b00 = s_base[0][0][p], b01 = s_base[0][1][p];
            const int b02 = s_base[0][2][p], b03 = s_base[0][3][p];
            const int b10 = s_base[1][0][p], b11 = s_base[1][1][p];
            const int b12 = s_base[1][2][p], b13 = s_base[1][3][p];
            const float w00 = s_wt[0][0][p], w01 = s_wt[0][1][p];
            const float w02 = s_wt[0][2][p], w03 = s_wt[0][3][p];
            const float w10 = s_wt[1][0][p], w11 = s_wt[1][1][p];
            const float w12 = s_wt[1][2][p], w13 = s_wt[1][3][p];

            const float fr = ftr[(size_t)(h * Ww + p) * Cc + c];
            const float a1 = w00 * ftr[b00 + c] + w01 * ftr[b01 + c] +
                             w02 * ftr[b02 + c] + w03 * ftr[b03 + c];
            const float a2 = w10 * ftr[b10 + c] + w11 * ftr[b11 + c] +
                             w12 * ftr[b12 + c] + w13 * ftr[b13 + c];
            const float s  = fr + a1 + a2;
            const float q  = fr * fr + a1 * a1 + a2 * a2;
            const float sc = s * cnt;
            s_tile[c][p] = q * cnt - sc * sc;
        }
    }
    __syncthreads();

    // ---- Phase 3 ----
#pragma unroll
    for (int idx = tid; idx < Cc * Ww; idx += BDIM) {
        const int cc = idx / Ww;
        const int p  = idx - cc * Ww;
        out[(9 + cc) * DHW + rowbase + p] = s_tile[cc][p];
    }
}

// ---------------------------------------------------------------------------
// fallback (no workspace needed) — only used if ws_size is too small
// ---------------------------------------------------------------------------
__global__ void __launch_bounds__(BDIM) ge_direct_kernel(
    const float* __restrict__ imgs, const float* __restrict__ feats,
    const float* __restrict__ proj, const float* __restrict__ depthv,
    float* __restrict__ out)
{
    const int idx = blockIdx.x * BDIM + threadIdx.x;
    if (idx >= NPIX) return;
    const int w = idx % Ww;
    const int t = idx / Ww;
    const int h = t % Hh;
    const int d = t / Hh;
    const int ohw = h * Ww + w;

    int offs[2][4];
    float wts[2][4];
    float msum;
    compute_warp(proj, depthv[d], (float)w, (float)h, offs, wts, msum);

    const int obase = d * HW + ohw;
#pragma unroll
    for (int c = 0; c < 3; ++c)
        out[c * DHW + obase] = imgs[c * HW + ohw];

#pragma unroll
    for (int v = 0; v < 2; ++v) {
        const float* ib = imgs + (size_t)(v + 1) * 3 * HW;
#pragma unroll
        for (int c = 0; c < 3; ++c) {
            const float* p = ib + (size_t)c * HW;
            const float acc = wts[v][0] * p[offs[v][0]] + wts[v][1] * p[offs[v][1]] +
                              wts[v][2] * p[offs[v][2]] + wts[v][3] * p[offs[v][3]];
            out[(3 * (v + 1) + c) * DHW + obase] = acc;
        }
    }

    const float count = 1.0f / msum;
    const float* f0 = feats;
    const float* f1 = feats + (size_t)Cc * HW;
    const float* f2 = feats + (size_t)2 * Cc * HW;
#pragma unroll 8
    for (int c = 0; c < Cc; ++c) {
        const float fr = f0[(size_t)c * HW + ohw];
        const float* p1 = f1 + (size_t)c * HW;
        const float* p2 = f2 + (size_t)c * HW;
        const float a1 = wts[0][0] * p1[offs[0][0]] + wts[0][1] * p1[offs[0][1]] +
                         wts[0][2] * p1[offs[0][2]] + wts[0][3] * p1[offs[0][3]];
        const float a2 = wts[1][0] * p2[offs[1][0]] + wts[1][1] * p2[offs[1][1]] +
                         wts[1][2] * p2[offs[1][2]] + wts[1][3] * p2[offs[1][3]];
        const float s = fr + a1 + a2;
        const float sq = fr * fr + a1 * a1 + a2 * a2;
        const float sc = s * count;
        out[(3 * Vv + c) * DHW + obase] = sq * count - sc * sc;
    }
}

extern "C" void kernel_launch(void* const* d_in, const int* in_sizes, int n_in,
                              void* d_out, int out_size, void* d_ws, size_t ws_size,
                              hipStream_t stream)
{
    const float* imgs   = (const float*)d_in[0];
    const float* feats  = (const float*)d_in[1];
    const float* proj   = (const float*)d_in[2];
    const float* depthv = (const float*)d_in[3];
    float* out = (float*)d_out;

    const size_t need = (size_t)Vv * HW * Cc * sizeof(float);   // 7.08 MB

    if (ws_size >= need) {
        float* ftr = (float*)d_ws;
        dim3 g1(HW / 64, Vv);
        transpose_feats_kernel<<<g1, BDIM, 0, stream>>>(feats, ftr);
        ge_row_kernel<<<Dd * Hh, BDIM, 0, stream>>>(imgs, ftr, proj, depthv, out);
    } else {
        const int blocks = (NPIX + BDIM - 1) / BDIM;
        ge_direct_kernel<<<blocks, BDIM, 0, stream>>>(imgs, feats, proj, depthv, out);
    }
}